// Round 8
// baseline (183.890 us; speedup 1.0000x reference)
//
#include <hip/hip_runtime.h>
#include <hip/hip_bf16.h>

#define BATCH 8192
#define IN_F  2048
#define OUT_F 2048
#define QB    7.0f
#define EPSV  1e-5f
#define ASCALE 18.0f            // xq_i8 = round(xq * 18) in [-126,126]

typedef char  i8x4 __attribute__((ext_vector_type(4)));
typedef int   i32x4 __attribute__((ext_vector_type(4)));

#define AS1(p) ((__attribute__((address_space(1))) void*)(p))
#define AS3(p) ((__attribute__((address_space(3))) void*)(p))

// ---------------- Fused preprocessing, one WAVE per row ----------------
// (round-1 verified version, unchanged)
__global__ __launch_bounds__(256) void prep_kernel(const float* __restrict__ x,
                                                   const float* __restrict__ w,
                                                   char* __restrict__ xq,
                                                   char* __restrict__ wb,
                                                   float* __restrict__ gamaOut,
                                                   float* __restrict__ betaOut) {
  const int t = threadIdx.x;
  const int wave = t >> 6, lane = t & 63;
  const int rowId = blockIdx.x * 4 + wave;   // grid = (OUT_F + BATCH) / 4

  if (rowId < OUT_F) {
    const int row = rowId;
    const float4* wr = (const float4*)(w + (size_t)row * IN_F);
    float4 v[8];
#pragma unroll
    for (int j = 0; j < 8; ++j) v[j] = wr[lane + 64 * j];

    float s = 0.0f, sa = 0.0f;
#pragma unroll
    for (int j = 0; j < 8; ++j) {
      s  += v[j].x + v[j].y + v[j].z + v[j].w;
      sa += fabsf(v[j].x) + fabsf(v[j].y) + fabsf(v[j].z) + fabsf(v[j].w);
    }
#pragma unroll
    for (int off = 32; off > 0; off >>= 1) {
      s  += __shfl_xor(s, off, 64);
      sa += __shfl_xor(sa, off, 64);
    }
    const float mu = s * (1.0f / IN_F);
    if (lane == 0) betaOut[row] = sa * (1.0f / IN_F);

    char* wbr = wb + (size_t)row * IN_F;
    auto sgn = [&](float xv) -> char {
      float d = xv - mu;
      return (char)((d > 0.0f) ? 1 : (d < 0.0f ? -1 : 0));
    };
#pragma unroll
    for (int j = 0; j < 8; ++j) {
      i8x4 q = { sgn(v[j].x), sgn(v[j].y), sgn(v[j].z), sgn(v[j].w) };
      ((i8x4*)wbr)[lane + 64 * j] = q;
    }
  } else {
    const int row = rowId - OUT_F;
    const float4* xr = (const float4*)(x + (size_t)row * IN_F);
    float4 v[8];
#pragma unroll
    for (int j = 0; j < 8; ++j) v[j] = xr[lane + 64 * j];

    float s = 0.0f, s2 = 0.0f;
#pragma unroll
    for (int j = 0; j < 8; ++j) {
      s  += v[j].x + v[j].y + v[j].z + v[j].w;
      s2 += v[j].x * v[j].x + v[j].y * v[j].y + v[j].z * v[j].z + v[j].w * v[j].w;
    }
#pragma unroll
    for (int off = 32; off > 0; off >>= 1) {
      s  += __shfl_xor(s, off, 64);
      s2 += __shfl_xor(s2, off, 64);
    }
    const float mu   = s * (1.0f / IN_F);
    const float rstd = rsqrtf(fmaxf(s2 * (1.0f / IN_F) - mu * mu, 0.0f) + EPSV);

    float ad = 0.0f;
#pragma unroll
    for (int j = 0; j < 8; ++j) {
      ad = fmaxf(ad, fmaxf(fmaxf(fabsf(v[j].x - mu), fabsf(v[j].y - mu)),
                           fmaxf(fabsf(v[j].z - mu), fabsf(v[j].w - mu))));
    }
#pragma unroll
    for (int off = 32; off > 0; off >>= 1) ad = fmaxf(ad, __shfl_xor(ad, off, 64));
    const float g = fmaxf(ad * rstd, EPSV);
    if (lane == 0) gamaOut[row] = g;

    const float c  = rstd * (QB * ASCALE) / g;     // rstd * 126/g
    const float lo = (-QB + EPSV) * ASCALE, hi = (QB - EPSV) * ASCALE;
    auto qz = [&](float vv) -> char {
      return (char)__float2int_rn(fminf(fmaxf((vv - mu) * c, lo), hi));
    };
    char* xqr = xq + (size_t)row * IN_F;
#pragma unroll
    for (int j = 0; j < 8; ++j) {
      i8x4 q = { qz(v[j].x), qz(v[j].y), qz(v[j].z), qz(v[j].w) };
      ((i8x4*)xqr)[lane + 64 * j] = q;
    }
  }
}

// ---------------- GEMM: i8, 256x128 tile, 4 waves, 2 blocks/CU -------------
// Combines the two proven winners: r5's big wave-tile (128x64/wave -> 64 MFMA
// per 8 staging loads) + r4's cross-block TLP (single-buffer 48 KB LDS ->
// 2 blocks/CU; one block's barrier drain/epilogue overlaps the other's MFMA,
// the m114 mechanism that beat explicit pipelining in r3/r6).
// Wave-level fragment geometry is byte-identical to r5 (rotation algebra
// holds: row&7 == fr&7 since wm in {0,128}). Staging = r4's 32-row pattern.
// Normal stores (NT reverted: measured WRITE 65.5 -> 84 MB, +6 us).
// Bijective XCD chunking over 512 blocks.
__global__ __launch_bounds__(256) void gemm_kernel(const char* __restrict__ A,
                                                   const char* __restrict__ B,
                                                   const float* __restrict__ beta,
                                                   const float* __restrict__ gama,
                                                   const float* __restrict__ bias,
                                                   float* __restrict__ out) {
  __shared__ __align__(16) char As[256 * 128];   // 32 KB
  __shared__ __align__(16) char Bs[128 * 128];   // 16 KB

  const int t = threadIdx.x;
  const int wave = t >> 6, lane = t & 63;
  const int bid = blockIdx.x;
  const int swz = (bid & 7) * 64 + (bid >> 3);    // bijective (512 % 8 == 0)
  const int mBase = (swz >> 4) * 256;             // 32 m-tiles
  const int nBase = (swz & 15) * 128;             // 16 n-tiles
  const int wm = (wave >> 1) * 128;               // 2 wave-rows
  const int wn = (wave & 1) * 64;                 // 2 wave-cols

  i32x4 acc[8][4];
#pragma unroll
  for (int i = 0; i < 8; ++i)
#pragma unroll
    for (int j = 0; j < 4; ++j) {
      i32x4 z = {0, 0, 0, 0};
      acc[i][j] = z;
    }

  // ---- staging: instr j covers rows j*32 + wave*8 + (lane>>3); slot = lane&7
  // holds global chunk (slot - row)&7; row&7 == lane>>3 (bases mult of 8)
  const int lr = lane >> 3;
  const int ls = lane & 7;
  const int gch = (ls - lr) & 7;
  const char* aG[8];
  const char* bG[4];
  int aOff[8];
  int bOff[4];
#pragma unroll
  for (int j = 0; j < 8; ++j) {
    const int rowInTile = j * 32 + wave * 8 + lr;
    aG[j] = A + (size_t)(mBase + rowInTile) * IN_F + gch * 16;
    aOff[j] = (j * 32 + wave * 8) * 128;   // wave-uniform; HW adds lane*16B
  }
#pragma unroll
  for (int j = 0; j < 4; ++j) {
    const int rowInTile = j * 32 + wave * 8 + lr;
    bG[j] = B + (size_t)(nBase + rowInTile) * IN_F + gch * 16;
    bOff[j] = (j * 32 + wave * 8) * 128;
  }

  // ---- fragment: A[m=lane&15][k=(lane>>4)*16+j]; LDS slot = (kh + fr) & 7
  const int fr = lane & 15;
  const int kq = lane >> 4;            // 0..3
  const char* aF = As + (wm + fr) * 128;
  const char* bF = Bs + (wn + fr) * 128;
  int koff[2];
#pragma unroll
  for (int ks = 0; ks < 2; ++ks) koff[ks] = ((ks * 4 + kq + fr) & 7) * 16;

  for (int k0 = 0; k0 < IN_F; k0 += 128) {
#pragma unroll
    for (int j = 0; j < 8; ++j)
      __builtin_amdgcn_global_load_lds(AS1(aG[j] + k0), AS3(As + aOff[j]), 16, 0, 0);
#pragma unroll
    for (int j = 0; j < 4; ++j)
      __builtin_amdgcn_global_load_lds(AS1(bG[j] + k0), AS3(Bs + bOff[j]), 16, 0, 0);
    __syncthreads();

#pragma unroll
    for (int ks = 0; ks < 2; ++ks) {
      i32x4 af[8], bf[4];
#pragma unroll
      for (int mi = 0; mi < 8; ++mi) af[mi] = *(const i32x4*)(aF + mi * 16 * 128 + koff[ks]);
#pragma unroll
      for (int ni = 0; ni < 4; ++ni) bf[ni] = *(const i32x4*)(bF + ni * 16 * 128 + koff[ks]);
#pragma unroll
      for (int mi = 0; mi < 8; ++mi)
#pragma unroll
        for (int ni = 0; ni < 4; ++ni)
          acc[mi][ni] = __builtin_amdgcn_mfma_i32_16x16x64_i8(af[mi], bf[ni], acc[mi][ni], 0, 0, 0);
    }
    __syncthreads();
  }

  // ---- epilogue: C/D layout col = lane&15, row = (lane>>4)*4 + reg
  const float qinv = 1.0f / (QB * ASCALE);
  const int orow0 = mBase + wm + (kq << 2);
  const int ocol0 = nBase + wn + fr;
#pragma unroll
  for (int mi = 0; mi < 8; ++mi) {
    const int rbase = orow0 + mi * 16;
    const float g0 = gama[rbase + 0] * qinv;
    const float g1 = gama[rbase + 1] * qinv;
    const float g2 = gama[rbase + 2] * qinv;
    const float g3 = gama[rbase + 3] * qinv;
#pragma unroll
    for (int ni = 0; ni < 4; ++ni) {
      const int c = ocol0 + ni * 16;
      const float bsc = beta[c];
      const float bv  = bias[c];
      float* op = out + (size_t)rbase * OUT_F + c;
      op[0 * OUT_F] = (float)acc[mi][ni][0] * (bsc * g0) + bv;
      op[1 * OUT_F] = (float)acc[mi][ni][1] * (bsc * g1) + bv;
      op[2 * OUT_F] = (float)acc[mi][ni][2] * (bsc * g2) + bv;
      op[3 * OUT_F] = (float)acc[mi][ni][3] * (bsc * g3) + bv;
    }
  }
}

extern "C" void kernel_launch(void* const* d_in, const int* in_sizes, int n_in,
                              void* d_out, int out_size, void* d_ws, size_t ws_size,
                              hipStream_t stream) {
  const float* x      = (const float*)d_in[0];
  const float* weight = (const float*)d_in[1];
  const float* bias   = (const float*)d_in[2];
  float* out = (float*)d_out;

  char* ws = (char*)d_ws;
  char* wbin = ws;                                                  // 4 MB
  char* xq   = ws + (size_t)OUT_F * IN_F;                           // 16 MB
  float* betaW = (float*)(ws + (size_t)OUT_F * IN_F + (size_t)BATCH * IN_F);
  float* gamaX = betaW + OUT_F;

  prep_kernel<<<(OUT_F + BATCH) / 4, 256, 0, stream>>>(x, weight, xq, wbin, gamaX, betaW);
  gemm_kernel<<<(BATCH / 256) * (OUT_F / 128), 256, 0, stream>>>(xq, wbin, betaW, gamaX, bias, out);
}

// Round 9
// 159.064 us; speedup vs baseline: 1.1561x; 1.1561x over previous
//
#include <hip/hip_runtime.h>
#include <hip/hip_bf16.h>

#define BATCH 8192
#define IN_F  2048
#define OUT_F 2048
#define QB    7.0f
#define EPSV  1e-5f
#define ASCALE 18.0f            // xq_i8 = round(xq * 18) in [-126,126]

typedef char  i8x4 __attribute__((ext_vector_type(4)));
typedef int   i32x4 __attribute__((ext_vector_type(4)));

#define AS1(p) ((__attribute__((address_space(1))) void*)(p))
#define AS3(p) ((__attribute__((address_space(3))) void*)(p))

// ---------------- Fused preprocessing, one WAVE per row ----------------
// (round-1 verified version, unchanged)
__global__ __launch_bounds__(256) void prep_kernel(const float* __restrict__ x,
                                                   const float* __restrict__ w,
                                                   char* __restrict__ xq,
                                                   char* __restrict__ wb,
                                                   float* __restrict__ gamaOut,
                                                   float* __restrict__ betaOut) {
  const int t = threadIdx.x;
  const int wave = t >> 6, lane = t & 63;
  const int rowId = blockIdx.x * 4 + wave;   // grid = (OUT_F + BATCH) / 4

  if (rowId < OUT_F) {
    const int row = rowId;
    const float4* wr = (const float4*)(w + (size_t)row * IN_F);
    float4 v[8];
#pragma unroll
    for (int j = 0; j < 8; ++j) v[j] = wr[lane + 64 * j];

    float s = 0.0f, sa = 0.0f;
#pragma unroll
    for (int j = 0; j < 8; ++j) {
      s  += v[j].x + v[j].y + v[j].z + v[j].w;
      sa += fabsf(v[j].x) + fabsf(v[j].y) + fabsf(v[j].z) + fabsf(v[j].w);
    }
#pragma unroll
    for (int off = 32; off > 0; off >>= 1) {
      s  += __shfl_xor(s, off, 64);
      sa += __shfl_xor(sa, off, 64);
    }
    const float mu = s * (1.0f / IN_F);
    if (lane == 0) betaOut[row] = sa * (1.0f / IN_F);

    char* wbr = wb + (size_t)row * IN_F;
    auto sgn = [&](float xv) -> char {
      float d = xv - mu;
      return (char)((d > 0.0f) ? 1 : (d < 0.0f ? -1 : 0));
    };
#pragma unroll
    for (int j = 0; j < 8; ++j) {
      i8x4 q = { sgn(v[j].x), sgn(v[j].y), sgn(v[j].z), sgn(v[j].w) };
      ((i8x4*)wbr)[lane + 64 * j] = q;
    }
  } else {
    const int row = rowId - OUT_F;
    const float4* xr = (const float4*)(x + (size_t)row * IN_F);
    float4 v[8];
#pragma unroll
    for (int j = 0; j < 8; ++j) v[j] = xr[lane + 64 * j];

    float s = 0.0f, s2 = 0.0f;
#pragma unroll
    for (int j = 0; j < 8; ++j) {
      s  += v[j].x + v[j].y + v[j].z + v[j].w;
      s2 += v[j].x * v[j].x + v[j].y * v[j].y + v[j].z * v[j].z + v[j].w * v[j].w;
    }
#pragma unroll
    for (int off = 32; off > 0; off >>= 1) {
      s  += __shfl_xor(s, off, 64);
      s2 += __shfl_xor(s2, off, 64);
    }
    const float mu   = s * (1.0f / IN_F);
    const float rstd = rsqrtf(fmaxf(s2 * (1.0f / IN_F) - mu * mu, 0.0f) + EPSV);

    float ad = 0.0f;
#pragma unroll
    for (int j = 0; j < 8; ++j) {
      ad = fmaxf(ad, fmaxf(fmaxf(fabsf(v[j].x - mu), fabsf(v[j].y - mu)),
                           fmaxf(fabsf(v[j].z - mu), fabsf(v[j].w - mu))));
    }
#pragma unroll
    for (int off = 32; off > 0; off >>= 1) ad = fmaxf(ad, __shfl_xor(ad, off, 64));
    const float g = fmaxf(ad * rstd, EPSV);
    if (lane == 0) gamaOut[row] = g;

    const float c  = rstd * (QB * ASCALE) / g;     // rstd * 126/g
    const float lo = (-QB + EPSV) * ASCALE, hi = (QB - EPSV) * ASCALE;
    auto qz = [&](float vv) -> char {
      return (char)__float2int_rn(fminf(fmaxf((vv - mu) * c, lo), hi));
    };
    char* xqr = xq + (size_t)row * IN_F;
#pragma unroll
    for (int j = 0; j < 8; ++j) {
      i8x4 q = { qz(v[j].x), qz(v[j].y), qz(v[j].z), qz(v[j].w) };
      ((i8x4*)xqr)[lane + 64 * j] = q;
    }
  }
}

// ---------------- GEMM: i8, 256x256 tile, BK=128, dbuf prefetch ------------
// r5 proven structure (best measured: 46.3 us). ONE change (r9): the compute
// phase now issues ALL 24 fragment ds_reads (both ks halves) BEFORE any MFMA.
// Rationale: r5's K-step measured ~4800 cyc ~= 2600 (MFMA pipe) + 2300 (LDS
// pipe) -> the pipes were serializing. Hoisting ks=1's reads lets the LDS
// pipe drain under ks=0's 32 MFMAs (fine-grained lgkmcnt does the rest).
// Costs ~96 extra live VGPRs; acc(128) already pins 2 waves/SIMD, budget 256.
// Everything else identical: rotation LDS scheme (0 conflicts), bijective
// XCD chunking (FETCH 24.7 MB), normal stores (NT measured worse).
__global__ __launch_bounds__(512) void gemm_kernel(const char* __restrict__ A,
                                                   const char* __restrict__ B,
                                                   const float* __restrict__ beta,
                                                   const float* __restrict__ gama,
                                                   const float* __restrict__ bias,
                                                   float* __restrict__ out) {
  __shared__ __align__(16) char As[2 * 256 * 128];
  __shared__ __align__(16) char Bs[2 * 256 * 128];

  const int t = threadIdx.x;
  const int wave = t >> 6, lane = t & 63;
  const int bid = blockIdx.x;
  const int swz = (bid & 7) * 32 + (bid >> 3);    // bijective (256 % 8 == 0)
  const int mBase = (swz >> 3) * 256;             // 32 m-tiles
  const int nBase = (swz & 7) * 256;              // 8 n-tiles
  const int wm = (wave >> 2) * 128;               // 2 wave-rows
  const int wn = (wave & 3) * 64;                 // 4 wave-cols

  i32x4 acc[8][4];
#pragma unroll
  for (int i = 0; i < 8; ++i)
#pragma unroll
    for (int j = 0; j < 4; ++j) {
      i32x4 z = {0, 0, 0, 0};
      acc[i][j] = z;
    }

  // ---- staging: instr j covers rows j*64 + wave*8 + (lane>>3); slot = lane&7
  // holds global chunk (slot - row)&7; row&7 == lane>>3 (bases are mult of 8)
  const int lr = lane >> 3;
  const int ls = lane & 7;
  const int gch = (ls - lr) & 7;
  const char* aG[4];
  const char* bG[4];
  int lOff[4];
#pragma unroll
  for (int j = 0; j < 4; ++j) {
    const int rowInTile = j * 64 + wave * 8 + lr;
    aG[j] = A + (size_t)(mBase + rowInTile) * IN_F + gch * 16;
    bG[j] = B + (size_t)(nBase + rowInTile) * IN_F + gch * 16;
    lOff[j] = (j * 64 + wave * 8) * 128;   // wave-uniform; HW adds lane*16B
  }

  // ---- fragment: A[m=lane&15][k=(lane>>4)*16+j]; LDS slot = (kh + fr) & 7
  const int fr = lane & 15;
  const int kq = lane >> 4;            // 0..3
  int koff[2];
#pragma unroll
  for (int ks = 0; ks < 2; ++ks) koff[ks] = ((ks * 4 + kq + fr) & 7) * 16;

  auto stage = [&](int k0, int buf) {
#pragma unroll
    for (int j = 0; j < 4; ++j) {
      __builtin_amdgcn_global_load_lds(AS1(aG[j] + k0), AS3(As + buf * 32768 + lOff[j]), 16, 0, 0);
      __builtin_amdgcn_global_load_lds(AS1(bG[j] + k0), AS3(Bs + buf * 32768 + lOff[j]), 16, 0, 0);
    }
  };
  auto compute = [&](int buf) {
    const char* aF = As + buf * 32768 + (wm + fr) * 128;
    const char* bF = Bs + buf * 32768 + (wn + fr) * 128;
    i32x4 af0[8], bf0[4], af1[8], bf1[4];
    // ---- issue ALL fragment reads first (both ks halves) ----
#pragma unroll
    for (int ni = 0; ni < 4; ++ni) bf0[ni] = *(const i32x4*)(bF + ni * 2048 + koff[0]);
#pragma unroll
    for (int mi = 0; mi < 8; ++mi) af0[mi] = *(const i32x4*)(aF + mi * 2048 + koff[0]);
#pragma unroll
    for (int ni = 0; ni < 4; ++ni) bf1[ni] = *(const i32x4*)(bF + ni * 2048 + koff[1]);
#pragma unroll
    for (int mi = 0; mi < 8; ++mi) af1[mi] = *(const i32x4*)(aF + mi * 2048 + koff[1]);
    // ---- MFMA ks=0 runs while ks=1 reads drain on the LDS pipe ----
#pragma unroll
    for (int mi = 0; mi < 8; ++mi)
#pragma unroll
      for (int ni = 0; ni < 4; ++ni)
        acc[mi][ni] = __builtin_amdgcn_mfma_i32_16x16x64_i8(af0[mi], bf0[ni], acc[mi][ni], 0, 0, 0);
#pragma unroll
    for (int mi = 0; mi < 8; ++mi)
#pragma unroll
      for (int ni = 0; ni < 4; ++ni)
        acc[mi][ni] = __builtin_amdgcn_mfma_i32_16x16x64_i8(af1[mi], bf1[ni], acc[mi][ni], 0, 0, 0);
  };

  // prologue: tile 0 -> buf 0
  stage(0, 0);
  __syncthreads();                 // implicit vmcnt(0) drain + barrier

  int cur = 0;
  for (int k0 = 128; k0 < IN_F; k0 += 128) {
    stage(k0, cur ^ 1);            // issue next-tile loads (other buffer)
    compute(cur);                  // load latency hides under 64 MFMA/wave
    __syncthreads();               // drain next-tile loads + barrier
    cur ^= 1;
  }
  compute(cur);                    // last tile, no prefetch

  // ---- epilogue: C/D layout col = lane&15, row = (lane>>4)*4 + reg
  const float qinv = 1.0f / (QB * ASCALE);
  const int orow0 = mBase + wm + (kq << 2);
  const int ocol0 = nBase + wn + fr;
#pragma unroll
  for (int mi = 0; mi < 8; ++mi) {
    const int rbase = orow0 + mi * 16;
    const float g0 = gama[rbase + 0] * qinv;
    const float g1 = gama[rbase + 1] * qinv;
    const float g2 = gama[rbase + 2] * qinv;
    const float g3 = gama[rbase + 3] * qinv;
#pragma unroll
    for (int ni = 0; ni < 4; ++ni) {
      const int c = ocol0 + ni * 16;
      const float bsc = beta[c];
      const float bv  = bias[c];
      float* op = out + (size_t)rbase * OUT_F + c;
      op[0 * OUT_F] = (float)acc[mi][ni][0] * (bsc * g0) + bv;
      op[1 * OUT_F] = (float)acc[mi][ni][1] * (bsc * g1) + bv;
      op[2 * OUT_F] = (float)acc[mi][ni][2] * (bsc * g2) + bv;
      op[3 * OUT_F] = (float)acc[mi][ni][3] * (bsc * g3) + bv;
    }
  }
}

extern "C" void kernel_launch(void* const* d_in, const int* in_sizes, int n_in,
                              void* d_out, int out_size, void* d_ws, size_t ws_size,
                              hipStream_t stream) {
  const float* x      = (const float*)d_in[0];
  const float* weight = (const float*)d_in[1];
  const float* bias   = (const float*)d_in[2];
  float* out = (float*)d_out;

  char* ws = (char*)d_ws;
  char* wbin = ws;                                                  // 4 MB
  char* xq   = ws + (size_t)OUT_F * IN_F;                           // 16 MB
  float* betaW = (float*)(ws + (size_t)OUT_F * IN_F + (size_t)BATCH * IN_F);
  float* gamaX = betaW + OUT_F;

  prep_kernel<<<(OUT_F + BATCH) / 4, 256, 0, stream>>>(x, weight, xq, wbin, gamaX, betaW);
  gemm_kernel<<<(OUT_F / 256) * (BATCH / 256), 512, 0, stream>>>(xq, wbin, betaW, gamaX, bias, out);
}

// Round 10
// 158.323 us; speedup vs baseline: 1.1615x; 1.0047x over previous
//
#include <hip/hip_runtime.h>
#include <hip/hip_bf16.h>

#define BATCH 8192
#define IN_F  2048
#define OUT_F 2048
#define QB    7.0f
#define EPSV  1e-5f
#define ASCALE 18.0f            // xq_i8 = round(xq * 18) in [-126,126]

typedef char  i8x4 __attribute__((ext_vector_type(4)));
typedef int   i32x4 __attribute__((ext_vector_type(4)));

#define AS1(p) ((__attribute__((address_space(1))) void*)(p))
#define AS3(p) ((__attribute__((address_space(3))) void*)(p))

__device__ __forceinline__ float waveReduceSum(float v) {
#pragma unroll
  for (int off = 32; off > 0; off >>= 1) v += __shfl_xor(v, off, 64);
  return v;
}
__device__ __forceinline__ float waveReduceMax(float v) {
#pragma unroll
  for (int off = 32; off > 0; off >>= 1) v = fmaxf(v, __shfl_xor(v, off, 64));
  return v;
}

// ---------------- Fused preprocessing (r0 block-per-row, REVERTED) ---------
// Ledger audit: prep+overhead was 98.7 us with this version (r0) vs 113.3
// +-1.2 us with the r1 wave-per-row rewrite (constant across r1/r4/r5/r9).
// The r1 "fix" was a ~14 us regression masked by a simultaneous gemm gain.
// blocks [0, OUT_F): weight row -> wbin i8 {-1,0,1} (exact), beta
// blocks [OUT_F, OUT_F+BATCH): LN+clip row -> xq i8 = round(clip*18), gama
__global__ __launch_bounds__(256) void prep_kernel(const float* __restrict__ x,
                                                   const float* __restrict__ w,
                                                   char* __restrict__ xq,
                                                   char* __restrict__ wb,
                                                   float* __restrict__ gamaOut,
                                                   float* __restrict__ betaOut) {
  __shared__ float red[8];
  const int t = threadIdx.x;
  const int wave = t >> 6, lane = t & 63;

  if (blockIdx.x < OUT_F) {
    const int row = blockIdx.x;
    const float* wr = w + (size_t)row * IN_F;
    float4 v0 = ((const float4*)wr)[t];
    float4 v1 = ((const float4*)wr)[t + 256];
    float s  = v0.x + v0.y + v0.z + v0.w + v1.x + v1.y + v1.z + v1.w;
    float sa = fabsf(v0.x) + fabsf(v0.y) + fabsf(v0.z) + fabsf(v0.w)
             + fabsf(v1.x) + fabsf(v1.y) + fabsf(v1.z) + fabsf(v1.w);
    float wsum = waveReduceSum(s);
    float wsa  = waveReduceSum(sa);
    if (lane == 0) { red[wave] = wsum; red[4 + wave] = wsa; }
    __syncthreads();
    const float mu   = (red[0] + red[1] + red[2] + red[3]) * (1.0f / IN_F);
    const float beta = (red[4] + red[5] + red[6] + red[7]) * (1.0f / IN_F);
    if (t == 0) betaOut[row] = beta;

    char* wbr = wb + (size_t)row * IN_F;
    auto sgn = [&](float xv) -> char {
      float d = xv - mu;
      return (char)((d > 0.0f) ? 1 : (d < 0.0f ? -1 : 0));
    };
    i8x4 q0 = { sgn(v0.x), sgn(v0.y), sgn(v0.z), sgn(v0.w) };
    i8x4 q1 = { sgn(v1.x), sgn(v1.y), sgn(v1.z), sgn(v1.w) };
    ((i8x4*)wbr)[t]       = q0;
    ((i8x4*)wbr)[t + 256] = q1;
  } else {
    const int row = blockIdx.x - OUT_F;
    const float* xr = x + (size_t)row * IN_F;
    float4 v0 = ((const float4*)xr)[t];
    float4 v1 = ((const float4*)xr)[t + 256];
    float s  = v0.x + v0.y + v0.z + v0.w + v1.x + v1.y + v1.z + v1.w;
    float s2 = v0.x*v0.x + v0.y*v0.y + v0.z*v0.z + v0.w*v0.w
             + v1.x*v1.x + v1.y*v1.y + v1.z*v1.z + v1.w*v1.w;
    float wsum  = waveReduceSum(s);
    float wsum2 = waveReduceSum(s2);
    if (lane == 0) { red[wave] = wsum; red[4 + wave] = wsum2; }
    __syncthreads();
    const float mu  = (red[0] + red[1] + red[2] + red[3]) * (1.0f / IN_F);
    const float ex2 = (red[4] + red[5] + red[6] + red[7]) * (1.0f / IN_F);
    const float rstd = rsqrtf(fmaxf(ex2 - mu * mu, 0.0f) + EPSV);

    float n[8];
    n[0] = (v0.x - mu) * rstd; n[1] = (v0.y - mu) * rstd;
    n[2] = (v0.z - mu) * rstd; n[3] = (v0.w - mu) * rstd;
    n[4] = (v1.x - mu) * rstd; n[5] = (v1.y - mu) * rstd;
    n[6] = (v1.z - mu) * rstd; n[7] = (v1.w - mu) * rstd;
    float amax = 0.0f;
#pragma unroll
    for (int j = 0; j < 8; ++j) amax = fmaxf(amax, fabsf(n[j]));

    __syncthreads();
    float wmax = waveReduceMax(amax);
    if (lane == 0) red[wave] = wmax;
    __syncthreads();
    const float g = fmaxf(fmaxf(fmaxf(red[0], red[1]), fmaxf(red[2], red[3])), EPSV);
    if (t == 0) gamaOut[row] = g;

    // xq_i8 = round( clip(xln*7/g, -(7-eps), 7-eps) * 18 )  (|.| <= 126)
    const float qs = (QB * ASCALE) / g;           // 126/g
    const float lo = (-QB + EPSV) * ASCALE, hi = (QB - EPSV) * ASCALE;
    auto qz = [&](float v) -> char {
      return (char)__float2int_rn(fminf(fmaxf(v * qs, lo), hi));
    };
    char* xqr = xq + (size_t)row * IN_F;
    i8x4 q0 = { qz(n[0]), qz(n[1]), qz(n[2]), qz(n[3]) };
    i8x4 q1 = { qz(n[4]), qz(n[5]), qz(n[6]), qz(n[7]) };
    ((i8x4*)xqr)[t]       = q0;
    ((i8x4*)xqr)[t + 256] = q1;
  }
}

// ---------------- GEMM: i8, 256x256 tile, BK=128, dbuf prefetch ------------
// (r9 version, unchanged — best measured total)
__global__ __launch_bounds__(512) void gemm_kernel(const char* __restrict__ A,
                                                   const char* __restrict__ B,
                                                   const float* __restrict__ beta,
                                                   const float* __restrict__ gama,
                                                   const float* __restrict__ bias,
                                                   float* __restrict__ out) {
  __shared__ __align__(16) char As[2 * 256 * 128];
  __shared__ __align__(16) char Bs[2 * 256 * 128];

  const int t = threadIdx.x;
  const int wave = t >> 6, lane = t & 63;
  const int bid = blockIdx.x;
  const int swz = (bid & 7) * 32 + (bid >> 3);    // bijective (256 % 8 == 0)
  const int mBase = (swz >> 3) * 256;             // 32 m-tiles
  const int nBase = (swz & 7) * 256;              // 8 n-tiles
  const int wm = (wave >> 2) * 128;               // 2 wave-rows
  const int wn = (wave & 3) * 64;                 // 4 wave-cols

  i32x4 acc[8][4];
#pragma unroll
  for (int i = 0; i < 8; ++i)
#pragma unroll
    for (int j = 0; j < 4; ++j) {
      i32x4 z = {0, 0, 0, 0};
      acc[i][j] = z;
    }

  // ---- staging: instr j covers rows j*64 + wave*8 + (lane>>3); slot = lane&7
  // holds global chunk (slot - row)&7; row&7 == lane>>3 (bases are mult of 8)
  const int lr = lane >> 3;
  const int ls = lane & 7;
  const int gch = (ls - lr) & 7;
  const char* aG[4];
  const char* bG[4];
  int lOff[4];
#pragma unroll
  for (int j = 0; j < 4; ++j) {
    const int rowInTile = j * 64 + wave * 8 + lr;
    aG[j] = A + (size_t)(mBase + rowInTile) * IN_F + gch * 16;
    bG[j] = B + (size_t)(nBase + rowInTile) * IN_F + gch * 16;
    lOff[j] = (j * 64 + wave * 8) * 128;   // wave-uniform; HW adds lane*16B
  }

  // ---- fragment: A[m=lane&15][k=(lane>>4)*16+j]; LDS slot = (kh + fr) & 7
  const int fr = lane & 15;
  const int kq = lane >> 4;            // 0..3
  int koff[2];
#pragma unroll
  for (int ks = 0; ks < 2; ++ks) koff[ks] = ((ks * 4 + kq + fr) & 7) * 16;

  auto stage = [&](int k0, int buf) {
#pragma unroll
    for (int j = 0; j < 4; ++j) {
      __builtin_amdgcn_global_load_lds(AS1(aG[j] + k0), AS3(As + buf * 32768 + lOff[j]), 16, 0, 0);
      __builtin_amdgcn_global_load_lds(AS1(bG[j] + k0), AS3(Bs + buf * 32768 + lOff[j]), 16, 0, 0);
    }
  };
  auto compute = [&](int buf) {
    const char* aF = As + buf * 32768 + (wm + fr) * 128;
    const char* bF = Bs + buf * 32768 + (wn + fr) * 128;
    i32x4 af0[8], bf0[4], af1[8], bf1[4];
#pragma unroll
    for (int ni = 0; ni < 4; ++ni) bf0[ni] = *(const i32x4*)(bF + ni * 2048 + koff[0]);
#pragma unroll
    for (int mi = 0; mi < 8; ++mi) af0[mi] = *(const i32x4*)(aF + mi * 2048 + koff[0]);
#pragma unroll
    for (int ni = 0; ni < 4; ++ni) bf1[ni] = *(const i32x4*)(bF + ni * 2048 + koff[1]);
#pragma unroll
    for (int mi = 0; mi < 8; ++mi) af1[mi] = *(const i32x4*)(aF + mi * 2048 + koff[1]);
#pragma unroll
    for (int mi = 0; mi < 8; ++mi)
#pragma unroll
      for (int ni = 0; ni < 4; ++ni)
        acc[mi][ni] = __builtin_amdgcn_mfma_i32_16x16x64_i8(af0[mi], bf0[ni], acc[mi][ni], 0, 0, 0);
#pragma unroll
    for (int mi = 0; mi < 8; ++mi)
#pragma unroll
      for (int ni = 0; ni < 4; ++ni)
        acc[mi][ni] = __builtin_amdgcn_mfma_i32_16x16x64_i8(af1[mi], bf1[ni], acc[mi][ni], 0, 0, 0);
  };

  // prologue: tile 0 -> buf 0
  stage(0, 0);
  __syncthreads();                 // implicit vmcnt(0) drain + barrier

  int cur = 0;
  for (int k0 = 128; k0 < IN_F; k0 += 128) {
    stage(k0, cur ^ 1);            // issue next-tile loads (other buffer)
    compute(cur);                  // load latency hides under 64 MFMA/wave
    __syncthreads();               // drain next-tile loads + barrier
    cur ^= 1;
  }
  compute(cur);                    // last tile, no prefetch

  // ---- epilogue: C/D layout col = lane&15, row = (lane>>4)*4 + reg
  const float qinv = 1.0f / (QB * ASCALE);
  const int orow0 = mBase + wm + (kq << 2);
  const int ocol0 = nBase + wn + fr;
#pragma unroll
  for (int mi = 0; mi < 8; ++mi) {
    const int rbase = orow0 + mi * 16;
    const float g0 = gama[rbase + 0] * qinv;
    const float g1 = gama[rbase + 1] * qinv;
    const float g2 = gama[rbase + 2] * qinv;
    const float g3 = gama[rbase + 3] * qinv;
#pragma unroll
    for (int ni = 0; ni < 4; ++ni) {
      const int c = ocol0 + ni * 16;
      const float bsc = beta[c];
      const float bv  = bias[c];
      float* op = out + (size_t)rbase * OUT_F + c;
      op[0 * OUT_F] = (float)acc[mi][ni][0] * (bsc * g0) + bv;
      op[1 * OUT_F] = (float)acc[mi][ni][1] * (bsc * g1) + bv;
      op[2 * OUT_F] = (float)acc[mi][ni][2] * (bsc * g2) + bv;
      op[3 * OUT_F] = (float)acc[mi][ni][3] * (bsc * g3) + bv;
    }
  }
}

extern "C" void kernel_launch(void* const* d_in, const int* in_sizes, int n_in,
                              void* d_out, int out_size, void* d_ws, size_t ws_size,
                              hipStream_t stream) {
  const float* x      = (const float*)d_in[0];
  const float* weight = (const float*)d_in[1];
  const float* bias   = (const float*)d_in[2];
  float* out = (float*)d_out;

  char* ws = (char*)d_ws;
  char* wbin = ws;                                                  // 4 MB
  char* xq   = ws + (size_t)OUT_F * IN_F;                           // 16 MB
  float* betaW = (float*)(ws + (size_t)OUT_F * IN_F + (size_t)BATCH * IN_F);
  float* gamaX = betaW + OUT_F;

  prep_kernel<<<OUT_F + BATCH, 256, 0, stream>>>(x, weight, xq, wbin, gamaX, betaW);
  gemm_kernel<<<(OUT_F / 256) * (BATCH / 256), 512, 0, stream>>>(xq, wbin, betaW, gamaX, bias, out);
}